// Round 1
// baseline (315.778 us; speedup 1.0000x reference)
//
#include <hip/hip_runtime.h>

#define SPATIAL_SCALE 0.25f
#define PH_ 7
#define PW_ 7
#define NBINS 49
#define NSAMP 196          // 49 bins * 4 samples
#define C_ 256
#define H_ 256
#define W_ 256
#define HW_ (H_ * W_)
#define RES_STRIDE 257     // 49-row result buffer, padded to break bank conflicts

// ---------------------------------------------------------------------------
// Transpose NCHW -> NHWC (per batch: [C][HW] -> [HW][C]), 32x32 LDS tiles.
// ---------------------------------------------------------------------------
__global__ __launch_bounds__(256) void transpose_nchw_nhwc(
    const float* __restrict__ in, float* __restrict__ out) {
  __shared__ float tile[32][33];
  const int b  = blockIdx.z;
  const int c0 = blockIdx.y * 32;
  const int p0 = blockIdx.x * 32;
  const float* src = in  + (size_t)b * C_ * HW_;
  float*       dst = out + (size_t)b * HW_ * C_;
  const int tx = threadIdx.x;   // 0..31
  const int ty = threadIdx.y;   // 0..7
#pragma unroll
  for (int i = 0; i < 32; i += 8)
    tile[ty + i][tx] = src[(size_t)(c0 + ty + i) * HW_ + p0 + tx];
  __syncthreads();
#pragma unroll
  for (int i = 0; i < 32; i += 8)
    dst[(size_t)(p0 + ty + i) * C_ + c0 + tx] = tile[tx][ty + i];
}

// ---------------------------------------------------------------------------
// Main kernel: one block per roi, thread = channel.
// NHWC=true  : feat is channel-last (from transpose), loads coalesced.
// NHWC=false : fallback reading original NCHW directly (slow path, only if
//              ws_size is too small for the transposed copy).
// ---------------------------------------------------------------------------
template <bool NHWC>
__global__ __launch_bounds__(256) void roi_align_rotated_kernel(
    const float* __restrict__ feat, const float* __restrict__ rois,
    float* __restrict__ out) {
  __shared__ int4   d_off[NSAMP];
  __shared__ float4 d_w[NSAMP];
  __shared__ float  res[NBINS * RES_STRIDE];

  const int r = blockIdx.x;
  const int t = threadIdx.x;

  // ---- Phase 1: sample descriptors (positions + bilinear weights) ----
  if (t < NSAMP) {
    const float* rp = rois + r * 6;
    const int   b  = (int)rp[0];
    const float cx = rp[1] * SPATIAL_SCALE - 0.5f;
    const float cy = rp[2] * SPATIAL_SCALE - 0.5f;
    const float rw = rp[3] * SPATIAL_SCALE;
    const float rh = rp[4] * SPATIAL_SCALE;
    const float th = rp[5];                 // CLOCKWISE=False
    float sn, cs;
    sincosf(th, &sn, &cs);
    const float bin_h = rh / (float)PH_;
    const float bin_w = rw / (float)PW_;

    const int s   = t;          // s = bin*4 + sub
    const int bin = s >> 2;
    const int sub = s & 3;
    const int ph  = bin / 7;
    const int pw  = bin - ph * 7;
    const int iy  = sub >> 1;
    const int ix  = sub & 1;

    const float yy = -0.5f * rh + ((float)ph + ((float)iy + 0.5f) * 0.5f) * bin_h;
    const float xx = -0.5f * rw + ((float)pw + ((float)ix + 0.5f) * 0.5f) * bin_w;
    float y = yy * cs - xx * sn + cy;
    float x = yy * sn + xx * cs + cx;

    const bool valid = (y > -1.0f) && (y < (float)H_) &&
                       (x > -1.0f) && (x < (float)W_);
    // clamp to [0, H-1]; reproduces ref's condy/condx -> ly=lx=0 path
    y = fminf(fmaxf(y, 0.0f), (float)(H_ - 1));
    x = fminf(fmaxf(x, 0.0f), (float)(W_ - 1));
    const int yl = (int)y;
    const int xl = (int)x;
    const int yh = min(yl + 1, H_ - 1);
    const int xh = min(xl + 1, W_ - 1);
    const float ly = y - (float)yl, lx = x - (float)xl;
    const float hy = 1.0f - ly, hx = 1.0f - lx;
    float w11 = hy * hx, w12 = hy * lx, w21 = ly * hx, w22 = ly * lx;
    if (!valid) { w11 = w12 = w21 = w22 = 0.0f; }

    int4 off;
    if (NHWC) {
      off.x = ((b * H_ + yl) * W_ + xl) * C_;
      off.y = ((b * H_ + yl) * W_ + xh) * C_;
      off.z = ((b * H_ + yh) * W_ + xl) * C_;
      off.w = ((b * H_ + yh) * W_ + xh) * C_;
    } else {
      const int base = b * C_ * HW_;
      off.x = base + yl * W_ + xl;
      off.y = base + yl * W_ + xh;
      off.z = base + yh * W_ + xl;
      off.w = base + yh * W_ + xh;
    }
    d_off[s] = off;
    d_w[s]   = make_float4(w11, w12, w21, w22);
  }
  __syncthreads();

  // ---- Phase 2: per-channel accumulation over all 49 bins ----
  const int c    = t;
  const int coff = NHWC ? c : c * HW_;
  for (int bin = 0; bin < NBINS; ++bin) {
    float acc = 0.0f;
#pragma unroll
    for (int sub = 0; sub < 4; ++sub) {
      const int4   o = d_off[bin * 4 + sub];
      const float4 w = d_w[bin * 4 + sub];
      acc += w.x * feat[o.x + coff];
      acc += w.y * feat[o.y + coff];
      acc += w.z * feat[o.z + coff];
      acc += w.w * feat[o.w + coff];
    }
    res[bin * RES_STRIDE + c] = acc * 0.25f;
  }
  __syncthreads();

  // ---- Phase 3: coalesced contiguous write of the roi's output slab ----
  float* outr = out + (size_t)r * (C_ * NBINS);
#pragma unroll 1
  for (int i = t; i < C_ * NBINS; i += 256) {
    const int cc = i / NBINS;
    const int bb = i - cc * NBINS;
    outr[i] = res[bb * RES_STRIDE + cc];
  }
}

// ---------------------------------------------------------------------------
extern "C" void kernel_launch(void* const* d_in, const int* in_sizes, int n_in,
                              void* d_out, int out_size, void* d_ws, size_t ws_size,
                              hipStream_t stream) {
  const float* feat = (const float*)d_in[0];
  const float* rois = (const float*)d_in[1];
  float* out = (float*)d_out;
  const int n_rois  = in_sizes[1] / 6;
  const int n_batch = in_sizes[0] / (C_ * HW_);

  const size_t need = (size_t)n_batch * C_ * HW_ * sizeof(float);
  if (ws_size >= need) {
    float* feat_t = (float*)d_ws;
    dim3 tb(32, 8);
    dim3 tg(HW_ / 32, C_ / 32, n_batch);
    hipLaunchKernelGGL(transpose_nchw_nhwc, tg, tb, 0, stream, feat, feat_t);
    hipLaunchKernelGGL((roi_align_rotated_kernel<true>), dim3(n_rois), dim3(256),
                       0, stream, feat_t, rois, out);
  } else {
    hipLaunchKernelGGL((roi_align_rotated_kernel<false>), dim3(n_rois), dim3(256),
                       0, stream, feat, rois, out);
  }
}